// Round 3
// baseline (212.955 us; speedup 1.0000x reference)
//
#include <hip/hip_runtime.h>
#include <math.h>

// Capsule routing B=32, N=1024(j), D=256(k), NC=32(i), DC=64(d). Factored
// (no u_hat), MFMA 16x16x32 bf16:
//   delta[j,i] = U[b,j,:].w[:,i]    (k_pass phase D: A=U row-major, B=w hi/lo)
//   e = exp(logit), sef = sum_j e   (fp32 on reduced C-frags)
//   t[i,k] = sum_j e[i,j] U[j,k]    (k_pass phase T: A=e hi/lo, B=U direct)
//   s = tW_i; v = s*rsqrt(||s||^2+eps*sef^2); w = W_i v
// Round-10: Ubf bf16 pre-conversion (neutral; kept).
// Round-11: atomic t/sef accumulation (slightly negative alone; kept as the
// enabler for Round-12).
// Round-12: LAUNCH FUSION. Rounds 10-11 proved traffic is not the bottleneck
// (L2/L3-resident); fixed per-kernel cost is. k_sv(mode1) is fused into the
// tail of k_pass via a per-bg last-block-done counter: the 16th sibling block
// (all p-slices of one bg) runs s/v/w for its 16 rows (one il per wave,
// full-K lanes loops, __shfl broadcast, t staged into s_red). 6 -> 4 launches.
// 77.3 KB LDS -> 2 blocks/CU. No spin-waits, no grid.sync, graph-safe.

typedef short v8s __attribute__((ext_vector_type(8)));
typedef short v4s __attribute__((ext_vector_type(4)));
typedef float v4f __attribute__((ext_vector_type(4)));

__device__ __forceinline__ unsigned short f2bf(float x) {
    unsigned u = __float_as_uint(x);
    u = u + 0x7fffu + ((u >> 16) & 1u);
    return (unsigned short)(u >> 16);
}
__device__ __forceinline__ float bf2f(unsigned short h) {
    return __uint_as_float(((unsigned)h) << 16);
}

// ---------------------------------------------------------------------------
// k_init: bid<512: colsum partials t0p[b][q][k] (iter-0 uniform softmax) AND
//         bf16 conversion of U into Ubf; bid>=512: transpose W -> WT.
__global__ __launch_bounds__(256) void k_init(const float* __restrict__ U,
                                              const float* __restrict__ W,
                                              float* __restrict__ t0p,
                                              float* __restrict__ WT,
                                              short* __restrict__ Ubf) {
    int bid = blockIdx.x, tid = threadIdx.x;
    if (bid < 512) {
        int b = bid >> 4, q = bid & 15;
        int row0 = (b << 10) + (q << 6);
        const float* Up = U + (row0 << 8) + tid;
        short* Ub = Ubf + (row0 << 8) + tid;
        float acc = 0.f;
        #pragma unroll 8
        for (int jl = 0; jl < 64; ++jl) {
            float x = Up[jl << 8];
            acc += x;
            Ub[jl << 8] = (short)f2bf(x);
        }
        t0p[(b << 12) + (q << 8) + tid] = acc * (1.0f / 1024.0f);
    } else {
        __shared__ float tile[64 * 65];
        int tix = bid - 512;                 // 0..127
        int k0 = (tix >> 5) << 6, c0 = (tix & 31) << 6;
        int cc = tid & 63, g4 = tid >> 6;
        #pragma unroll
        for (int r = 0; r < 16; ++r) {
            int kk = (g4 << 4) + r;
            tile[kk * 65 + cc] = W[(k0 + kk) * 2048 + c0 + cc];
        }
        __syncthreads();
        int kk = tid & 63;
        #pragma unroll
        for (int r = 0; r < 16; ++r) {
            int c = (g4 << 4) + r;
            WT[(c0 + c) * 256 + k0 + kk] = tile[kk * 65 + c];
        }
    }
}

// ---------------------------------------------------------------------------
// k_sv0: iteration-0 (uniform softmax): t row from t0p partials, sef=1;
// s = tW_i; v = squash; w = W_i v -> wbt hi/lo. Also zeroes the atomic t/sef
// accumulators and the per-bg counters for pass 0. grid 1024, block 256.
__global__ __launch_bounds__(256) void k_sv0(const float* __restrict__ t0p,
                                             float* __restrict__ t,
                                             float* __restrict__ sef,
                                             int* __restrict__ ctr,
                                             const float* __restrict__ W,
                                             const float* __restrict__ WT,
                                             short* __restrict__ wbt_h,
                                             short* __restrict__ wbt_l) {
    __shared__ float t_lds[256];
    __shared__ float spart[256];
    __shared__ __align__(16) float v_lds[64];
    __shared__ __align__(16) v4f spartw[256];
    int bid = blockIdx.x, tid = threadIdx.x;
    int b = bid >> 5, iG = bid & 31;
    int bg = (b << 1) | (iG >> 4), il = iG & 15;
    int row = (bg << 4) + il;

    const float* tb = t0p + (b << 12) + tid;
    float acc = 0.f;
    #pragma unroll
    for (int q = 0; q < 16; ++q) acc += tb[q << 8];
    // zero the atomic accumulators + counters for pass 0
    t[(row << 8) + tid] = 0.f;
    if (tid == 0) sef[row] = 0.f;
    if (tid == 0 && il == 0) ctr[bg] = 0;
    t_lds[tid] = acc;
    __syncthreads();

    // s-phase: (d = tid&63, kq = tid>>6)
    int d = tid & 63, kq = tid >> 6;
    const float* Wc = W + ((kq << 6) * 2048) + (iG << 6) + d;
    float s = 0.f;
    #pragma unroll 4
    for (int kk = 0; kk < 64; ++kk)
        s += t_lds[(kq << 6) + kk] * Wc[kk * 2048];
    spart[tid] = s;
    __syncthreads();

    if (tid < 64) {
        float sv = spart[tid] + spart[tid + 64] + spart[tid + 128] + spart[tid + 192];
        float n2 = sv * sv;
        #pragma unroll
        for (int m = 1; m < 64; m <<= 1) n2 += __shfl_xor(n2, m, 64);
        float v = sv * rsqrtf(n2 + 1e-7f);   // sef = 1 at iter 0
        v_lds[tid] = v;
    }
    __syncthreads();

    // w-phase
    int k4 = tid & 63, dq = tid >> 6;
    const float4* WT4 = (const float4*)WT;
    v4f wp = {0.f, 0.f, 0.f, 0.f};
    #pragma unroll
    for (int dd = 0; dd < 16; ++dd) {
        float vv = v_lds[(dq << 4) + dd];
        float4 wt = WT4[((iG << 6) + (dq << 4) + dd) * 64 + k4];
        wp.x += vv * wt.x; wp.y += vv * wt.y; wp.z += vv * wt.z; wp.w += vv * wt.w;
    }
    spartw[(dq << 6) + k4] = wp;
    __syncthreads();
    if (tid < 64) {
        v4f w = spartw[tid] + spartw[64 + tid] + spartw[128 + tid] + spartw[192 + tid];
        float wv4[4] = {w.x, w.y, w.z, w.w};
        unsigned short wh[4], wl[4];
        #pragma unroll
        for (int e = 0; e < 4; ++e) {
            wh[e] = f2bf(wv4[e]);
            wl[e] = f2bf(wv4[e] - bf2f(wh[e]));
        }
        int base = (row << 8) + (tid << 2);
        *(v4s*)&wbt_h[base] = (v4s){(short)wh[0], (short)wh[1], (short)wh[2], (short)wh[3]};
        *(v4s*)&wbt_l[base] = (v4s){(short)wl[0], (short)wl[1], (short)wl[2], (short)wl[3]};
    }
}

// ---------------------------------------------------------------------------
// k_pass fused: block = (b, p = 64-j slice, g2), grid 1024x1024.
// Main body: stage Ubf/wbt -> phase D -> logits/exp -> phase T (atomic t/sef).
// Tail: per-bg counter; the 16th sibling block runs the s/v/w update for its
// bg's 16 rows (wave il = wv, lane = d or k4), writing wbt for the next pass
// or the final out. 3+2 barriers.
__global__ __launch_bounds__(1024, 8) void k_pass(const short* __restrict__ Ubf,
                                                  const short* __restrict__ wbt_h,
                                                  const short* __restrict__ wbt_l,
                                                  float* __restrict__ bmatg,
                                                  float* __restrict__ t,
                                                  float* __restrict__ sef,
                                                  int* __restrict__ ctr,
                                                  const float* __restrict__ W,
                                                  const float* __restrict__ WT,
                                                  float* __restrict__ out,
                                                  int addold, int writeOut) {
    __shared__ short s_U[64 * 268];      // 34,304 B [j][k] pad 12
    __shared__ short s_wh[16 * 264];     // 8,448
    __shared__ short s_wl[16 * 264];     // 8,448
    __shared__ short s_eh[16 * 72];      // 2,304  [i][j] pad 8
    __shared__ short s_el[16 * 72];      // 2,304
    __shared__ float s_red[16 * 320];    // 20,480 (reused as t_l in tail)
    __shared__ float s_sefp[16 * 16];    // 1,024
    __shared__ int s_last;               // total ~77.3 KB

    const int tid = threadIdx.x, wv = tid >> 6, lane = tid & 63;
    const int quad = lane >> 4, nn = lane & 15;
    const int blk = blockIdx.x;
    const int b = blk & 31, pg = blk >> 5;
    const int p = pg >> 1, g2 = pg & 1;
    const int bg = (b << 1) | g2;
    const int rowbase = (b << 10) + (p << 6);

    const int mt2 = wv & 3, jq = wv >> 2;
    const int rr = (jq << 2) + quad;
    const int jloc = (mt2 << 4) + rr;
    const int ga = (((bg << 10) + (p << 6) + jloc) << 4) + nn;
    float bold = 0.f;
    if (addold) bold = bmatg[ga];

    // stage w hi/lo (waves 0-7)
    if (tid < 512) {
        int row = tid >> 5, seg = tid & 31;
        int gidx = (((bg << 4) + row) << 8) + (seg << 3);
        *(v8s*)&s_wh[row * 264 + (seg << 3)] = *(const v8s*)(wbt_h + gidx);
        *(v8s*)&s_wl[row * 264 + (seg << 3)] = *(const v8s*)(wbt_l + gidx);
    }
    // stage U once from Ubf (bf16)
    {
        const short* Ub = Ubf + (rowbase << 8);
        int col = tid & 31, row0 = tid >> 5;
        v8s u0 = *(const v8s*)(Ub + (row0 << 8) + (col << 3));
        v8s u1 = *(const v8s*)(Ub + ((row0 + 32) << 8) + (col << 3));
        *(v4s*)&s_U[row0 * 268 + (col << 3)]            = __builtin_shufflevector(u0, u0, 0, 1, 2, 3);
        *(v4s*)&s_U[row0 * 268 + (col << 3) + 4]        = __builtin_shufflevector(u0, u0, 4, 5, 6, 7);
        *(v4s*)&s_U[(row0 + 32) * 268 + (col << 3)]     = __builtin_shufflevector(u1, u1, 0, 1, 2, 3);
        *(v4s*)&s_U[(row0 + 32) * 268 + (col << 3) + 4] = __builtin_shufflevector(u1, u1, 4, 5, 6, 7);
    }
    __syncthreads();

    // ---- phase D ----
    {
        const int mt = wv & 3, kq = wv >> 2;
        v4f dacc = {0.f, 0.f, 0.f, 0.f};
        #pragma unroll
        for (int c = 0; c < 2; ++c) {
            int kb = (kq << 6) + (c << 5) + (quad << 3);
            v8s a  = *(const v8s*)&s_U[((mt << 4) + nn) * 268 + kb];
            v8s bh = *(const v8s*)&s_wh[nn * 264 + kb];
            v8s bl = *(const v8s*)&s_wl[nn * 264 + kb];
            dacc = __builtin_amdgcn_mfma_f32_16x16x32_bf16(a, bh, dacc, 0, 0, 0);
            dacc = __builtin_amdgcn_mfma_f32_16x16x32_bf16(a, bl, dacc, 0, 0, 0);
        }
        #pragma unroll
        for (int r = 0; r < 4; ++r)
            s_red[wv * 320 + ((quad << 2) + r) * 20 + nn] = dacc[r];
    }
    __syncthreads();

    // ---- K-reduce + logits + exp ----
    {
        float val = bold;
        #pragma unroll
        for (int kq = 0; kq < 4; ++kq)
            val += s_red[((kq << 2) + mt2) * 320 + rr * 20 + nn];
        if (!addold) bmatg[ga] = val;
        float e = __expf(val);
        unsigned short eh = f2bf(e);
        s_eh[nn * 72 + jloc] = (short)eh;
        s_el[nn * 72 + jloc] = (short)f2bf(e - bf2f(eh));
        float se = e;
        se += __shfl_xor(se, 16, 64);
        se += __shfl_xor(se, 32, 64);
        if (lane < 16) s_sefp[(wv << 4) + lane] = se;
    }
    __syncthreads();

    // ---- phase T: atomic accumulation into t ----
    {
        v4f tacc = {0.f, 0.f, 0.f, 0.f};
        const int k0 = wv << 4;
        #pragma unroll
        for (int jc = 0; jc < 2; ++jc) {
            v8s aeh = *(const v8s*)&s_eh[nn * 72 + (jc << 5) + (quad << 3)];
            v8s ael = *(const v8s*)&s_el[nn * 72 + (jc << 5) + (quad << 3)];
            short bu[8];
            #pragma unroll
            for (int jj = 0; jj < 8; ++jj)
                bu[jj] = s_U[((jc << 5) + (quad << 3) + jj) * 268 + k0 + nn];
            v8s bf = (v8s){bu[0], bu[1], bu[2], bu[3], bu[4], bu[5], bu[6], bu[7]};
            tacc = __builtin_amdgcn_mfma_f32_16x16x32_bf16(aeh, bf, tacc, 0, 0, 0);
            tacc = __builtin_amdgcn_mfma_f32_16x16x32_bf16(ael, bf, tacc, 0, 0, 0);
        }
        #pragma unroll
        for (int r = 0; r < 4; ++r) {
            int i = (quad << 2) + r;
            unsafeAtomicAdd(&t[(((bg << 4) + i) << 8) + k0 + nn], tacc[r]);
        }
    }
    if (tid < 16) {
        float ss = 0.f;
        #pragma unroll
        for (int w = 0; w < 16; ++w) ss += s_sefp[(w << 4) + tid];
        unsafeAtomicAdd(&sef[(bg << 4) + tid], ss);
    }

    // ---- last-block-done gate (per bg: 16 sibling p-blocks) ----
    __syncthreads();           // drains all VMEM (atomics) before signalling
    if (tid == 0) {
        __threadfence();
        int old = __hip_atomic_fetch_add(&ctr[bg], 1, __ATOMIC_ACQ_REL,
                                         __HIP_MEMORY_SCOPE_AGENT);
        s_last = (old == 15);
        if (old == 15) ctr[bg] = 0;   // reset for next pass / next replay
    }
    __syncthreads();
    if (!s_last) return;

    // ================= fused sv tail: 16 waves, wave = il row =================
    float* t_l = (float*)s_red;              // 4096 floats
    #pragma unroll
    for (int r = 0; r < 4; ++r) {
        int o = (r << 10) + tid;             // 0..4095
        float xv = __hip_atomic_load(&t[(bg << 12) + o], __ATOMIC_RELAXED,
                                     __HIP_MEMORY_SCOPE_AGENT);
        t_l[o] = xv;
        if (!writeOut) t[(bg << 12) + o] = 0.f;   // re-zero for next pass
    }
    float sefv = __hip_atomic_load(&sef[(bg << 4) + wv], __ATOMIC_RELAXED,
                                   __HIP_MEMORY_SCOPE_AGENT);
    if (!writeOut && tid < 16) sef[(bg << 4) + tid] = 0.f;
    __syncthreads();

    // s-phase: wave wv handles il = wv; lane = d
    const int il = wv, iGt = ((bg & 1) << 4) | il;
    const float* Wc = W + iGt * 64 + lane;
    float sv = 0.f;
    #pragma unroll 8
    for (int kk = 0; kk < 256; ++kk)
        sv += t_l[(il << 8) + kk] * Wc[kk * 2048];
    float n2 = sv * sv;
    #pragma unroll
    for (int m = 1; m < 64; m <<= 1) n2 += __shfl_xor(n2, m, 64);
    float vv = sv * rsqrtf(n2 + 1e-7f * sefv * sefv);

    if (writeOut) {
        out[((bg >> 1) << 11) + (iGt << 6) + lane] = vv;
        return;
    }

    // w-phase: lane = k4; v[d] broadcast via shfl
    const float4* WT4 = (const float4*)WT;
    v4f wp = {0.f, 0.f, 0.f, 0.f};
    #pragma unroll 8
    for (int dd = 0; dd < 64; ++dd) {
        float vd = __shfl(vv, dd, 64);
        float4 wt = WT4[((iGt << 6) + dd) * 64 + lane];
        wp.x += vd * wt.x; wp.y += vd * wt.y; wp.z += vd * wt.z; wp.w += vd * wt.w;
    }
    unsigned short wh[4], wl[4];
    float wv4[4] = {wp.x, wp.y, wp.z, wp.w};
    #pragma unroll
    for (int e = 0; e < 4; ++e) {
        wh[e] = f2bf(wv4[e]);
        wl[e] = f2bf(wv4[e] - bf2f(wh[e]));
    }
    int base = (((bg << 4) + il) << 8) + (lane << 2);
    *(v4s*)&((short*)wbt_h)[base] = (v4s){(short)wh[0], (short)wh[1], (short)wh[2], (short)wh[3]};
    *(v4s*)&((short*)wbt_l)[base] = (v4s){(short)wl[0], (short)wl[1], (short)wl[2], (short)wl[3]};
}

// ---------------------------------------------------------------------------
extern "C" void kernel_launch(void* const* d_in, const int* in_sizes, int n_in,
                              void* d_out, int out_size, void* d_ws, size_t ws_size,
                              hipStream_t stream) {
    const float* U = (const float*)d_in[0];   // [32,1024,256]
    const float* W = (const float*)d_in[1];   // [256,2048]
    float* out = (float*)d_out;               // [32,32,64]
    float* ws = (float*)d_ws;

    float* t0p   = ws;                  // [32][16][256]      = 131,072
    float* WT    = t0p + 131072;        // [2048][256]        = 524,288
    float* bmatg = WT + 524288;         // [64][1024][16]     = 1,048,576
    float* t     = bmatg + 1048576;     // [64][16][256]      = 262,144 (atomic)
    float* sef   = t + 262144;          // [64][16]           = 1,024   (atomic)
    short* wbt_h = (short*)(sef + 1024);    // [64][16][256] shorts
    short* wbt_l = wbt_h + 262144;
    short* Ubf   = wbt_l + 262144;      // [32][1024][256] bf16 = 16.8 MB
    int*   ctr   = (int*)(Ubf + 8388608);   // [64] per-bg counters

    k_init<<<640, 256, 0, stream>>>(U, W, t0p, WT, Ubf);
    k_sv0<<<1024, 256, 0, stream>>>(t0p, t, sef, ctr, W, WT, wbt_h, wbt_l);
    k_pass<<<1024, 1024, 0, stream>>>((const short*)wbt_h == nullptr ? nullptr : Ubf,
                                      wbt_h, wbt_l, bmatg, t, sef, ctr,
                                      W, WT, out, 0, 0);
    k_pass<<<1024, 1024, 0, stream>>>(Ubf, wbt_h, wbt_l, bmatg, t, sef, ctr,
                                      W, WT, out, 1, 1);
}

// Round 5
// 134.159 us; speedup vs baseline: 1.5873x; 1.5873x over previous
//
#include <hip/hip_runtime.h>
#include <hip/hip_cooperative_groups.h>
#include <math.h>

namespace cg = cooperative_groups;

// Capsule routing B=32, N=1024(j), D=256(k), NC=32(i), DC=64(d). Factored
// (no u_hat), MFMA 16x16x32 bf16:
//   delta[j,i] = U[b,j,:].w[:,i]; e = exp(logit); t[i,k] = sum_j e[i,j] U[j,k]
//   s = tW_i; v = s*rsqrt(||s||^2 + eps*sef^2); w = W_i v
// Round-14: TWO paths, chosen at launch time with capture-safe queries:
//  - coop k_all (round-13 structure) ONLY if stream not capturing AND
//    occupancy >= 2 blocks/CU, with the launch return value CHECKED
//    (round-13's absmax=0.51=all-zero-out proved the coop launch silently
//    never ran; the return was ignored).
//  - fallback = proven 6-launch path, with k_pass g2-MERGED: grid 512
//    (32b x 16p), both capsule groups per block -> U staged once per block
//    (16.8 MB/pass not 33.6), one scheduling round (512 = 2/CU x 256 CU).

typedef short v8s __attribute__((ext_vector_type(8)));
typedef short v4s __attribute__((ext_vector_type(4)));
typedef float v4f __attribute__((ext_vector_type(4)));

__device__ __forceinline__ unsigned short f2bf(float x) {
    unsigned u = __float_as_uint(x);
    u = u + 0x7fffu + ((u >> 16) & 1u);
    return (unsigned short)(u >> 16);
}
__device__ __forceinline__ float bf2f(unsigned short h) {
    return __uint_as_float(((unsigned)h) << 16);
}

// ===========================================================================
// Fallback path kernels (proven round-1 lineage)
// ===========================================================================
__global__ __launch_bounds__(256) void k_init(const float* __restrict__ U,
                                              const float* __restrict__ W,
                                              float* __restrict__ t0p,
                                              float* __restrict__ WT,
                                              short* __restrict__ Ubf) {
    int bid = blockIdx.x, tid = threadIdx.x;
    if (bid < 512) {
        int b = bid >> 4, q = bid & 15;
        int row0 = (b << 10) + (q << 6);
        const float* Up = U + (row0 << 8) + tid;
        short* Ub = Ubf + (row0 << 8) + tid;
        float acc = 0.f;
        #pragma unroll 8
        for (int jl = 0; jl < 64; ++jl) {
            float x = Up[jl << 8];
            acc += x;
            Ub[jl << 8] = (short)f2bf(x);
        }
        t0p[(b << 12) + (q << 8) + tid] = acc * (1.0f / 1024.0f);
    } else {
        __shared__ float tile[64 * 65];
        int tix = bid - 512;                 // 0..127
        int k0 = (tix >> 5) << 6, c0 = (tix & 31) << 6;
        int cc = tid & 63, g4 = tid >> 6;
        #pragma unroll
        for (int r = 0; r < 16; ++r) {
            int kk = (g4 << 4) + r;
            tile[kk * 65 + cc] = W[(k0 + kk) * 2048 + c0 + cc];
        }
        __syncthreads();
        int kk = tid & 63;
        #pragma unroll
        for (int r = 0; r < 16; ++r) {
            int c = (g4 << 4) + r;
            WT[(c0 + c) * 256 + k0 + kk] = tile[kk * 65 + c];
        }
    }
}

__global__ __launch_bounds__(256) void k_sv(const float* __restrict__ t0p,
                                            const float* __restrict__ tpart,
                                            const float* __restrict__ sefpart,
                                            const float* __restrict__ W,
                                            const float* __restrict__ WT,
                                            short* __restrict__ wbt_h,
                                            short* __restrict__ wbt_l,
                                            float* __restrict__ out,
                                            int mode, int writeOut) {
    __shared__ float t_lds[256];
    __shared__ float spart[256];
    __shared__ __align__(16) float v_lds[64];
    __shared__ __align__(16) v4f spartw[256];
    __shared__ float sefv_s;
    int bid = blockIdx.x, tid = threadIdx.x;
    int b = bid >> 5, iG = bid & 31;
    int bg = (b << 1) | (iG >> 4), il = iG & 15;

    float acc = 0.f;
    if (mode == 0) {
        const float* tb = t0p + (b << 12) + tid;
        #pragma unroll
        for (int q = 0; q < 16; ++q) acc += tb[q << 8];
        if (tid == 0) sefv_s = 1.0f;
    } else {
        const float* tb = tpart + (((bg << 4) + il) << 8) + tid;
        #pragma unroll
        for (int p = 0; p < 16; ++p) acc += tb[p << 18];  // stride 64*16*256
        if (tid == 0) {
            float s = 0.f;
            #pragma unroll
            for (int p = 0; p < 16; ++p) s += sefpart[(p << 10) + (bg << 4) + il];
            sefv_s = s;
        }
    }
    t_lds[tid] = acc;
    __syncthreads();

    int d = tid & 63, kq = tid >> 6;
    const float* Wc = W + ((kq << 6) * 2048) + (iG << 6) + d;
    float s = 0.f;
    #pragma unroll 4
    for (int kk = 0; kk < 64; ++kk)
        s += t_lds[(kq << 6) + kk] * Wc[kk * 2048];
    spart[tid] = s;
    __syncthreads();

    if (tid < 64) {
        float sv = spart[tid] + spart[tid + 64] + spart[tid + 128] + spart[tid + 192];
        float n2 = sv * sv;
        #pragma unroll
        for (int m = 1; m < 64; m <<= 1) n2 += __shfl_xor(n2, m, 64);
        float sf = sefv_s;
        float v = sv * rsqrtf(n2 + 1e-7f * sf * sf);
        v_lds[tid] = v;
        if (writeOut) out[(bid << 6) + tid] = v;
    }
    __syncthreads();
    if (writeOut) return;

    int k4 = tid & 63, dq = tid >> 6;
    const float4* WT4 = (const float4*)WT;
    v4f wp = {0.f, 0.f, 0.f, 0.f};
    #pragma unroll
    for (int dd = 0; dd < 16; ++dd) {
        float vv = v_lds[(dq << 4) + dd];
        float4 wt = WT4[((iG << 6) + (dq << 4) + dd) * 64 + k4];
        wp.x += vv * wt.x; wp.y += vv * wt.y; wp.z += vv * wt.z; wp.w += vv * wt.w;
    }
    spartw[(dq << 6) + k4] = wp;
    __syncthreads();
    if (tid < 64) {
        v4f w = spartw[tid] + spartw[64 + tid] + spartw[128 + tid] + spartw[192 + tid];
        float wv4[4] = {w.x, w.y, w.z, w.w};
        unsigned short wh[4], wl[4];
        #pragma unroll
        for (int e = 0; e < 4; ++e) {
            wh[e] = f2bf(wv4[e]);
            wl[e] = f2bf(wv4[e] - bf2f(wh[e]));
        }
        int base = (((bg << 4) + il) << 8) + (tid << 2);
        *(v4s*)&wbt_h[base] = (v4s){(short)wh[0], (short)wh[1], (short)wh[2], (short)wh[3]};
        *(v4s*)&wbt_l[base] = (v4s){(short)wl[0], (short)wl[1], (short)wl[2], (short)wl[3]};
    }
}

// k_pass g2-merged: grid 512 (32b x 16p), block 1024. U staged ONCE, both
// capsule groups processed against it. Barriers: 1 + 3 per g2.
__global__ __launch_bounds__(1024, 8) void k_pass(const short* __restrict__ Ubf,
                                                  const short* __restrict__ wbt_h,
                                                  const short* __restrict__ wbt_l,
                                                  float* __restrict__ bmatg,
                                                  float* __restrict__ tpart_out,
                                                  float* __restrict__ sefpart_out,
                                                  int addold) {
    __shared__ short s_U[64 * 268];      // 34,304 B [j][k] pad 12
    __shared__ short s_wh[16 * 264];     // 8,448
    __shared__ short s_wl[16 * 264];     // 8,448
    __shared__ short s_eh[16 * 72];      // 2,304
    __shared__ short s_el[16 * 72];      // 2,304
    __shared__ float s_red[16 * 320];    // 20,480
    __shared__ float s_sefp[16 * 16];    // 1,024   total 77,312 B

    const int tid = threadIdx.x, wv = tid >> 6, lane = tid & 63;
    const int quad = lane >> 4, nn = lane & 15;
    const int blk = blockIdx.x;
    const int b = blk & 31, p = blk >> 5;
    const int rowbase = (b << 10) + (p << 6);

    const int mt2 = wv & 3, jq = wv >> 2;
    const int rr = (jq << 2) + quad;
    const int jloc = (mt2 << 4) + rr;

    // prefetch old logits for both groups
    float bold[2] = {0.f, 0.f};
    if (addold) {
        #pragma unroll
        for (int g2 = 0; g2 < 2; ++g2) {
            int bg = (b << 1) | g2;
            bold[g2] = bmatg[(((bg << 10) + (p << 6) + jloc) << 4) + nn];
        }
    }

    // stage U once from Ubf (bf16)
    {
        const short* Ub = Ubf + (rowbase << 8);
        int col = tid & 31, row0 = tid >> 5;
        v8s u0 = *(const v8s*)(Ub + (row0 << 8) + (col << 3));
        v8s u1 = *(const v8s*)(Ub + ((row0 + 32) << 8) + (col << 3));
        *(v4s*)&s_U[row0 * 268 + (col << 3)]            = __builtin_shufflevector(u0, u0, 0, 1, 2, 3);
        *(v4s*)&s_U[row0 * 268 + (col << 3) + 4]        = __builtin_shufflevector(u0, u0, 4, 5, 6, 7);
        *(v4s*)&s_U[(row0 + 32) * 268 + (col << 3)]     = __builtin_shufflevector(u1, u1, 0, 1, 2, 3);
        *(v4s*)&s_U[(row0 + 32) * 268 + (col << 3) + 4] = __builtin_shufflevector(u1, u1, 4, 5, 6, 7);
    }

    #pragma unroll
    for (int g2 = 0; g2 < 2; ++g2) {
        const int bg = (b << 1) | g2;
        // stage w hi/lo for this group (safe: nobody reads s_wh here;
        // the following barrier also covers the U-stage on g2=0)
        if (tid < 512) {
            int row = tid >> 5, seg = tid & 31;
            int gidx = (((bg << 4) + row) << 8) + (seg << 3);
            *(v8s*)&s_wh[row * 264 + (seg << 3)] = *(const v8s*)(wbt_h + gidx);
            *(v8s*)&s_wl[row * 264 + (seg << 3)] = *(const v8s*)(wbt_l + gidx);
        }
        __syncthreads();

        // phase D: wave = (mt = j-tile, kq = K-quarter)
        {
            const int mt = wv & 3, kq = wv >> 2;
            v4f dacc = {0.f, 0.f, 0.f, 0.f};
            #pragma unroll
            for (int c = 0; c < 2; ++c) {
                int kb = (kq << 6) + (c << 5) + (quad << 3);
                v8s a  = *(const v8s*)&s_U[((mt << 4) + nn) * 268 + kb];
                v8s bh = *(const v8s*)&s_wh[nn * 264 + kb];
                v8s bl = *(const v8s*)&s_wl[nn * 264 + kb];
                dacc = __builtin_amdgcn_mfma_f32_16x16x32_bf16(a, bh, dacc, 0, 0, 0);
                dacc = __builtin_amdgcn_mfma_f32_16x16x32_bf16(a, bl, dacc, 0, 0, 0);
            }
            #pragma unroll
            for (int r = 0; r < 4; ++r)
                s_red[wv * 320 + ((quad << 2) + r) * 20 + nn] = dacc[r];
        }
        __syncthreads();

        // K-reduce + logits + exp + sef partials
        {
            float val = bold[g2];
            #pragma unroll
            for (int kq = 0; kq < 4; ++kq)
                val += s_red[((kq << 2) + mt2) * 320 + rr * 20 + nn];
            if (!addold)
                bmatg[(((bg << 10) + (p << 6) + jloc) << 4) + nn] = val;
            float e = __expf(val);
            unsigned short eh = f2bf(e);
            s_eh[nn * 72 + jloc] = (short)eh;
            s_el[nn * 72 + jloc] = (short)f2bf(e - bf2f(eh));
            float se = e;
            se += __shfl_xor(se, 16, 64);
            se += __shfl_xor(se, 32, 64);
            if (lane < 16) s_sefp[(wv << 4) + lane] = se;
        }
        __syncthreads();

        // phase T: wave = 16-k N-tile
        {
            v4f tacc = {0.f, 0.f, 0.f, 0.f};
            const int k0 = wv << 4;
            #pragma unroll
            for (int jc = 0; jc < 2; ++jc) {
                v8s aeh = *(const v8s*)&s_eh[nn * 72 + (jc << 5) + (quad << 3)];
                v8s ael = *(const v8s*)&s_el[nn * 72 + (jc << 5) + (quad << 3)];
                short bu[8];
                #pragma unroll
                for (int jj = 0; jj < 8; ++jj)
                    bu[jj] = s_U[((jc << 5) + (quad << 3) + jj) * 268 + k0 + nn];
                v8s bf = (v8s){bu[0], bu[1], bu[2], bu[3], bu[4], bu[5], bu[6], bu[7]};
                tacc = __builtin_amdgcn_mfma_f32_16x16x32_bf16(aeh, bf, tacc, 0, 0, 0);
                tacc = __builtin_amdgcn_mfma_f32_16x16x32_bf16(ael, bf, tacc, 0, 0, 0);
            }
            #pragma unroll
            for (int r = 0; r < 4; ++r) {
                int i = (quad << 2) + r;
                tpart_out[(((((p << 6) + bg) << 4) + i) << 8) + k0 + nn] = tacc[r];
            }
        }
        if (tid < 16) {
            float ss = 0.f;
            #pragma unroll
            for (int w = 0; w < 16; ++w) ss += s_sefp[(w << 4) + tid];
            sefpart_out[(p << 10) + (bg << 4) + tid] = ss;
        }
    }
}

// ===========================================================================
// Cooperative single-kernel path (round-13 structure, launch now validated)
// ===========================================================================
#define OFF_WH   34304
#define OFF_WL   42752
#define OFF_EH   51200
#define OFF_EL   53504
#define OFF_RED  55808
#define OFF_SEFP 76288
#define OFF_SV   34304
#define SV_HALF  21504

__device__ __forceinline__ void sv_stage(
    char* smem, int bid, int tid,
    const float* __restrict__ t0p, const float* __restrict__ tpart,
    const float* __restrict__ sefpart, const float* __restrict__ W,
    const float* __restrict__ WT, short* __restrict__ wbt_h,
    short* __restrict__ wbt_l, float* __restrict__ out,
    int mode, int writeOut)
{
    const int half = tid >> 9, stid = tid & 511;
    const int u = (bid << 1) | half;
    const int b = u >> 5, iG = u & 31;
    const int bg = (b << 1) | (iG >> 4), il = iG & 15;
    char* base = smem + OFF_SV + half * SV_HALF;
    float* t_lds = (float*)base;
    float* spart = (float*)(base + 1024);
    float* v_lds = (float*)(base + 3072);
    float* sefv  = (float*)(base + 3328);
    v4f*  spartw = (v4f*)(base + 3344);

    {
        int col = stid & 255, h2 = stid >> 8;
        float acc = 0.f;
        if (mode == 0) {
            const float* tb = t0p + (b << 12) + col;
            #pragma unroll
            for (int q = 0; q < 8; ++q) acc += tb[((h2 << 3) + q) << 8];
        } else {
            const float* tb = tpart + (((bg << 4) + il) << 8) + col;
            #pragma unroll
            for (int p = 0; p < 8; ++p) acc += tb[((h2 << 3) + p) << 18];
        }
        spart[(h2 << 8) + col] = acc;
        if (stid == 0) {
            if (mode == 0) sefv[0] = 1.0f;
            else {
                float s = 0.f;
                #pragma unroll
                for (int p = 0; p < 16; ++p)
                    s += sefpart[(p << 10) + (bg << 4) + il];
                sefv[0] = s;
            }
        }
    }
    __syncthreads();
    if (stid < 256) t_lds[stid] = spart[stid] + spart[256 + stid];
    __syncthreads();

    {
        int d = stid & 63, kq = stid >> 6;
        const float* Wc = W + ((kq << 5) * 2048) + (iG << 6) + d;
        float s = 0.f;
        #pragma unroll 4
        for (int kk = 0; kk < 32; ++kk)
            s += t_lds[(kq << 5) + kk] * Wc[kk * 2048];
        spart[(kq << 6) + d] = s;
    }
    __syncthreads();
    if (stid < 64) {
        float sv = 0.f;
        #pragma unroll
        for (int q = 0; q < 8; ++q) sv += spart[(q << 6) + stid];
        float n2 = sv * sv;
        #pragma unroll
        for (int m = 1; m < 64; m <<= 1) n2 += __shfl_xor(n2, m, 64);
        float sf = sefv[0];
        float vv = sv * rsqrtf(n2 + 1e-7f * sf * sf);
        v_lds[stid] = vv;
        if (writeOut) out[(b << 11) + (iG << 6) + stid] = vv;
    }
    __syncthreads();
    if (writeOut) return;

    {
        int k4 = stid & 63, dq = stid >> 6;
        const float4* WT4 = (const float4*)WT;
        v4f wp = {0.f, 0.f, 0.f, 0.f};
        #pragma unroll
        for (int dd = 0; dd < 8; ++dd) {
            float vd = v_lds[(dq << 3) + dd];
            float4 wt = WT4[(((iG << 6) + (dq << 3) + dd) << 6) + k4];
            wp.x += vd * wt.x; wp.y += vd * wt.y;
            wp.z += vd * wt.z; wp.w += vd * wt.w;
        }
        spartw[(dq << 6) + k4] = wp;
    }
    __syncthreads();
    if (stid < 64) {
        v4f w = spartw[stid];
        #pragma unroll
        for (int q = 1; q < 8; ++q) w += spartw[(q << 6) + stid];
        float wv4[4] = {w.x, w.y, w.z, w.w};
        unsigned short wh[4], wl[4];
        #pragma unroll
        for (int e = 0; e < 4; ++e) {
            wh[e] = f2bf(wv4[e]);
            wl[e] = f2bf(wv4[e] - bf2f(wh[e]));
        }
        int bs = (((bg << 4) + il) << 8) + (stid << 2);
        *(v4s*)&wbt_h[bs] = (v4s){(short)wh[0], (short)wh[1], (short)wh[2], (short)wh[3]};
        *(v4s*)&wbt_l[bs] = (v4s){(short)wl[0], (short)wl[1], (short)wl[2], (short)wl[3]};
    }
    __syncthreads();
}

__device__ __forceinline__ void pass_stage(
    char* smem, int b, int pp, int tid,
    const short* __restrict__ wbt_h, const short* __restrict__ wbt_l,
    float* __restrict__ tpart, float* __restrict__ sefpart,
    float* vlog, int pass)
{
    short* s_U    = (short*)smem;
    short* s_wh   = (short*)(smem + OFF_WH);
    short* s_wl   = (short*)(smem + OFF_WL);
    short* s_eh   = (short*)(smem + OFF_EH);
    short* s_el   = (short*)(smem + OFF_EL);
    float* s_red  = (float*)(smem + OFF_RED);
    float* s_sefp = (float*)(smem + OFF_SEFP);

    const int wv = tid >> 6, lane = tid & 63;
    const int quad = lane >> 4, nn = lane & 15;
    const int mt2 = wv & 3, jq = wv >> 2;
    const int rr = (jq << 2) + quad;
    const int jloc = (mt2 << 4) + rr;

    #pragma unroll
    for (int g2 = 0; g2 < 2; ++g2) {
        const int bg = (b << 1) | g2;
        if (tid < 512) {
            int row = tid >> 5, seg = tid & 31;
            int gidx = (((bg << 4) + row) << 8) + (seg << 3);
            *(v8s*)&s_wh[row * 264 + (seg << 3)] = *(const v8s*)(wbt_h + gidx);
            *(v8s*)&s_wl[row * 264 + (seg << 3)] = *(const v8s*)(wbt_l + gidx);
        }
        __syncthreads();
        {
            const int mt = wv & 3, kq = wv >> 2;
            v4f dacc = {0.f, 0.f, 0.f, 0.f};
            #pragma unroll
            for (int c = 0; c < 2; ++c) {
                int kb = (kq << 6) + (c << 5) + (quad << 3);
                v8s a  = *(const v8s*)&s_U[((mt << 4) + nn) * 268 + kb];
                v8s bh = *(const v8s*)&s_wh[nn * 264 + kb];
                v8s bl = *(const v8s*)&s_wl[nn * 264 + kb];
                dacc = __builtin_amdgcn_mfma_f32_16x16x32_bf16(a, bh, dacc, 0, 0, 0);
                dacc = __builtin_amdgcn_mfma_f32_16x16x32_bf16(a, bl, dacc, 0, 0, 0);
            }
            #pragma unroll
            for (int r = 0; r < 4; ++r)
                s_red[wv * 320 + ((quad << 2) + r) * 20 + nn] = dacc[r];
        }
        __syncthreads();
        {
            float val = pass ? vlog[g2] : 0.f;
            #pragma unroll
            for (int kq = 0; kq < 4; ++kq)
                val += s_red[((kq << 2) + mt2) * 320 + rr * 20 + nn];
            if (!pass) vlog[g2] = val;
            float e = __expf(val);
            unsigned short eh = f2bf(e);
            s_eh[nn * 72 + jloc] = (short)eh;
            s_el[nn * 72 + jloc] = (short)f2bf(e - bf2f(eh));
            float se = e;
            se += __shfl_xor(se, 16, 64);
            se += __shfl_xor(se, 32, 64);
            if (lane < 16) s_sefp[(wv << 4) + lane] = se;
        }
        __syncthreads();
        {
            v4f tacc = {0.f, 0.f, 0.f, 0.f};
            const int k0 = wv << 4;
            #pragma unroll
            for (int jc = 0; jc < 2; ++jc) {
                v8s aeh = *(const v8s*)&s_eh[nn * 72 + (jc << 5) + (quad << 3)];
                v8s ael = *(const v8s*)&s_el[nn * 72 + (jc << 5) + (quad << 3)];
                short bu[8];
                #pragma unroll
                for (int jj = 0; jj < 8; ++jj)
                    bu[jj] = s_U[((jc << 5) + (quad << 3) + jj) * 268 + k0 + nn];
                v8s bf = (v8s){bu[0], bu[1], bu[2], bu[3], bu[4], bu[5], bu[6], bu[7]};
                tacc = __builtin_amdgcn_mfma_f32_16x16x32_bf16(aeh, bf, tacc, 0, 0, 0);
                tacc = __builtin_amdgcn_mfma_f32_16x16x32_bf16(ael, bf, tacc, 0, 0, 0);
            }
            #pragma unroll
            for (int r = 0; r < 4; ++r) {
                int i = (quad << 2) + r;
                tpart[(((((pp << 6) + bg) << 4) + i) << 8) + k0 + nn] = tacc[r];
            }
        }
        if (tid < 16) {
            float ss = 0.f;
            #pragma unroll
            for (int w = 0; w < 16; ++w) ss += s_sefp[(w << 4) + tid];
            sefpart[(pp << 10) + (bg << 4) + tid] = ss;
        }
        __syncthreads();
    }
}

__global__ __launch_bounds__(1024, 8) void k_all(
    const float* __restrict__ U, const float* __restrict__ W,
    float* __restrict__ out, float* __restrict__ t0p, float* __restrict__ WT,
    float* __restrict__ tpart, float* __restrict__ sefpart,
    short* __restrict__ wbt_h, short* __restrict__ wbt_l)
{
    __shared__ __align__(16) char smem[77312];
    cg::grid_group grid = cg::this_grid();
    const int tid = threadIdx.x, bid = blockIdx.x;
    const int b = bid & 31, pp = bid >> 5;
    float vlog[2];

    {   // S0: stage U -> s_U bf16 + colsum partials + W^T
        short* s_U = (short*)smem;
        v4f* cp4 = (v4f*)(smem + OFF_RED);
        const float4* U4 = (const float4*)U;
        const int rowbase = (b << 10) + (pp << 6);
        int col = tid & 63, row0 = tid >> 6;
        v4f psum = {0.f, 0.f, 0.f, 0.f};
        #pragma unroll
        for (int q = 0; q < 4; ++q) {
            float4 g = U4[(rowbase + row0 + (q << 4)) * 64 + col];
            psum.x += g.x; psum.y += g.y; psum.z += g.z; psum.w += g.w;
            *(v4s*)&s_U[(row0 + (q << 4)) * 268 + (col << 2)] =
                (v4s){(short)f2bf(g.x), (short)f2bf(g.y),
                      (short)f2bf(g.z), (short)f2bf(g.w)};
        }
        cp4[(row0 << 6) + col] = psum;
        __syncthreads();
        if (tid < 256) {
            const float* cp = (const float*)cp4;
            float acc = 0.f;
            #pragma unroll
            for (int r0 = 0; r0 < 16; ++r0) acc += cp[(r0 << 8) + tid];
            t0p[(b << 12) + (pp << 8) + tid] = acc * (1.0f / 1024.0f);
        }
        __syncthreads();
        if (bid < 128) {
            float* tile = (float*)(smem + OFF_RED);
            int k0 = (bid >> 5) << 6, c0 = (bid & 31) << 6;
            int cc = tid & 63, kk2 = tid >> 6;
            #pragma unroll
            for (int e = 0; e < 4; ++e) {
                int kk = kk2 + (e << 4);
                tile[kk * 65 + cc] = W[(k0 + kk) * 2048 + c0 + cc];
            }
            __syncthreads();
            int kk = tid & 63, c2 = tid >> 6;
            #pragma unroll
            for (int e = 0; e < 4; ++e) {
                int c = c2 + (e << 4);
                WT[(c0 + c) * 256 + k0 + kk] = tile[kk * 65 + c];
            }
        }
    }
    grid.sync();
    sv_stage((char*)smem, bid, tid, t0p, tpart, sefpart, W, WT,
             wbt_h, wbt_l, out, 0, 0);
    grid.sync();
    pass_stage((char*)smem, b, pp, tid, wbt_h, wbt_l, tpart, sefpart, vlog, 0);
    grid.sync();
    sv_stage((char*)smem, bid, tid, t0p, tpart, sefpart, W, WT,
             wbt_h, wbt_l, out, 1, 0);
    grid.sync();
    pass_stage((char*)smem, b, pp, tid, wbt_h, wbt_l, tpart, sefpart, vlog, 1);
    grid.sync();
    sv_stage((char*)smem, bid, tid, t0p, tpart, sefpart, W, WT,
             wbt_h, wbt_l, out, 1, 1);
}

// ---------------------------------------------------------------------------
extern "C" void kernel_launch(void* const* d_in, const int* in_sizes, int n_in,
                              void* d_out, int out_size, void* d_ws, size_t ws_size,
                              hipStream_t stream) {
    const float* U = (const float*)d_in[0];   // [32,1024,256]
    const float* W = (const float*)d_in[1];   // [256,2048]
    float* out = (float*)d_out;               // [32,32,64]
    float* ws = (float*)d_ws;

    float* t0p   = ws;                  // [32][16][256]     = 131,072
    float* WT    = t0p + 131072;        // [2048][256]       = 524,288
    float* bmatg = WT + 524288;         // [64][1024][16]    = 1,048,576
    float* tp    = bmatg + 1048576;     // [16][64][16][256] = 4,194,304
    float* sefp  = tp + 4194304;        // [16][64][16]      = 16,384
    short* wbt_h = (short*)(sefp + 16384);  // [64][16][256] shorts
    short* wbt_l = wbt_h + 262144;
    short* Ubf   = wbt_l + 262144;      // [32][1024][256] bf16

    // Try the cooperative single-kernel path only when provably safe:
    // not inside stream capture, and >= 2 resident 1024-thread blocks/CU.
    hipError_t cerr = hipErrorUnknown;
    hipStreamCaptureStatus cap = hipStreamCaptureStatusNone;
    (void)hipStreamIsCapturing(stream, &cap);
    if (cap == hipStreamCaptureStatusNone) {
        int maxb = 0;
        hipError_t oerr = hipOccupancyMaxActiveBlocksPerMultiprocessor(
            &maxb, (const void*)k_all, 1024, 0);
        if (oerr == hipSuccess && maxb >= 2) {
            void* args[] = {(void*)&U, (void*)&W, (void*)&out, (void*)&t0p,
                            (void*)&WT, (void*)&tp, (void*)&sefp,
                            (void*)&wbt_h, (void*)&wbt_l};
            cerr = hipLaunchCooperativeKernel((void*)k_all, dim3(512),
                                              dim3(1024), args, 0, stream);
        }
    }
    if (cerr != hipSuccess) {
        // Proven fallback: 6 launches, g2-merged k_pass (grid 512).
        k_init<<<640, 256, 0, stream>>>(U, W, t0p, WT, Ubf);
        k_sv<<<1024, 256, 0, stream>>>(t0p, tp, sefp, W, WT,
                                       wbt_h, wbt_l, out, 0, 0);
        k_pass<<<512, 1024, 0, stream>>>(Ubf, wbt_h, wbt_l, bmatg, tp, sefp, 0);
        k_sv<<<1024, 256, 0, stream>>>(t0p, tp, sefp, W, WT,
                                       wbt_h, wbt_l, out, 1, 0);
        k_pass<<<512, 1024, 0, stream>>>(Ubf, wbt_h, wbt_l, bmatg, tp, sefp, 1);
        k_sv<<<1024, 256, 0, stream>>>(t0p, tp, sefp, W, WT,
                                       wbt_h, wbt_l, out, 1, 1);
    }
}